// Round 11
// baseline (327.087 us; speedup 1.0000x reference)
//
#include <hip/hip_runtime.h>
#include <hip/hip_cooperative_groups.h>

namespace cg = cooperative_groups;

#define N_NODES 100000
#define N_EDGES 1600000
#define HID 32
#define BN_EPS 1e-5f

#define NW   13            // windows of 8192 nodes
#define WNS  8192
#define NB   208           // blocks (= NW * SPW)
#define NT   1024
#define EPS2 7693          // ceil(N_EDGES / NB)
#define SPW  16            // slices per window
#define SRC_MASK 0x1FFFFu

// ============================ fused cooperative kernel ============================

__global__ __launch_bounds__(1024, 1)
void fused_kernel(const int* __restrict__ srcp, const int* __restrict__ dstp,
                  const float* __restrict__ x, const float* __restrict__ W,
                  const float* __restrict__ bb, const float* __restrict__ gamma,
                  const float* __restrict__ beta, const float* __restrict__ prelu,
                  float* __restrict__ stats, int* __restrict__ cnt,
                  int* __restrict__ soff, int* __restrict__ tot,
                  int* __restrict__ wstart, unsigned* __restrict__ ebuf,
                  int* __restrict__ hpart, float* __restrict__ spart,
                  float4* __restrict__ xd, float4* __restrict__ S4,
                  float* __restrict__ out) {
    cg::grid_group grid = cg::this_grid();
    __shared__ __align__(16) unsigned char lds[WNS * 3 * 4];   // 96 KB scratch, re-used per phase
    int tid = threadIdx.x, bi = blockIdx.x;

    // ---- P1: zero stats; per-slice window counts (per-wave LDS rows) ----
    if (bi == 0 && tid < 16) stats[tid] = 0.f;
    {
        int (*wh)[NW] = (int(*)[NW])lds;   // [16][13]
        if (tid < 16 * NW) wh[tid / NW][tid % NW] = 0;
        __syncthreads();
        int wave = tid >> 6;
        int e0 = bi * EPS2, e1 = e0 + EPS2; if (e1 > N_EDGES) e1 = N_EDGES;
        for (int e = e0 + tid; e < e1; e += NT)
            atomicAdd(&wh[wave][dstp[e] >> 13], 1);
        __syncthreads();
        if (tid < NW) {
            int t = 0;
#pragma unroll
            for (int w = 0; w < 16; ++w) t += wh[w][tid];
            cnt[bi * NW + tid] = t;
        }
    }
    grid.sync();

    // ---- P2: blocks 0..12 -> parallel column scan over 208 slices ----
    if (bi < NW) {
        int* sc = (int*)lds;               // [256]
        int v = 0;
        if (tid < 256) {
            v = (tid < NB) ? cnt[tid * NW + bi] : 0;
            sc[tid] = v;
        }
        __syncthreads();
        for (int off = 1; off < 256; off <<= 1) {
            int u = 0;
            if (tid < 256 && tid >= off) u = sc[tid - off];
            __syncthreads();
            if (tid < 256) sc[tid] += u;
            __syncthreads();
        }
        if (tid < NB) soff[tid * NW + bi] = sc[tid] - v;
        if (tid == NB - 1) tot[bi] = sc[tid];
    }
    grid.sync();

    // ---- P3: place edges (ballot-ranked, window-contiguous ebuf) ----
    {
        int* curs = (int*)lds;             // [13]
        if (tid == 0) {
            int acc = 0;
            for (int b2 = 0; b2 < NW; ++b2) {
                if (bi == 0) wstart[b2] = acc;
                curs[b2] = acc + soff[bi * NW + b2];
                acc += tot[b2];
            }
            if (bi == 0) wstart[NW] = acc;
        }
        __syncthreads();
        int lane = tid & 63;
        int e0 = bi * EPS2, e1 = e0 + EPS2; if (e1 > N_EDGES) e1 = N_EDGES;
        for (int e = e0 + tid; e < e1; e += NT) {
            int d = dstp[e];
            int w = d >> 13;
            unsigned pk = ((unsigned)(d & (WNS - 1)) << 17) | (unsigned)srcp[e];
            int pos = 0;
#pragma unroll 1
            for (int bq = 0; bq < NW; ++bq) {
                unsigned long long m = __ballot(w == bq);
                if (w == bq) {
                    int rank = __popcll(m & ((1ull << lane) - 1ull));
                    int ldr = __ffsll((long long)m) - 1;
                    int wbase = 0;
                    if (lane == ldr) wbase = atomicAdd(&curs[bq], __popcll(m));
                    wbase = __shfl(wbase, ldr);
                    pos = wbase + rank;
                }
            }
            ebuf[pos] = pk;
        }
    }
    grid.sync();

    // ---- P4: per-(window,slice) degree partials via 32KB LDS hist ----
    {
        int* hist = (int*)lds;             // [8192]
        for (int j = tid; j < WNS; j += NT) hist[j] = 0;
        __syncthreads();
        int w = bi >> 4, sl = bi & 15;
        int e0 = wstart[w], e1w = wstart[w + 1];
        int len = e1w - e0, chunk = (len + SPW - 1) / SPW;
        int a0 = e0 + sl * chunk;
        int a1 = a0 + chunk; if (a1 > e1w) a1 = e1w;
        for (int e = a0 + tid; e < a1; e += NT)
            atomicAdd(&hist[ebuf[e] >> 17], 1);
        __syncthreads();
        int* dp = hpart + (size_t)bi * WNS;
        for (int j = tid; j < WNS; j += NT) dp[j] = hist[j];
    }
    grid.sync();

    // ---- P5: xd[n] = (x*rd, rd) from 16 partials ----
    {
        int n = bi * NT + tid;
        if (n < N_NODES) {
            int w = n >> 13, o = n & (WNS - 1);
            const int* hp = hpart + (size_t)(w * SPW) * WNS + o;
            int deg = 0;
#pragma unroll
            for (int sl = 0; sl < SPW; ++sl) deg += hp[(size_t)sl * WNS];
            float rd = rsqrtf(1.0f + (float)deg);
            xd[n] = make_float4(x[3 * n] * rd, x[3 * n + 1] * rd, x[3 * n + 2] * rd, rd);
        }
    }
    grid.sync();

    // ---- P6: per-(window,slice) S partials via 96KB LDS float accumulate ----
    {
        float* S = (float*)lds;            // [24576]
        for (int j = tid; j < WNS * 3; j += NT) S[j] = 0.f;
        __syncthreads();
        int w = bi >> 4, sl = bi & 15;
        int e0 = wstart[w], e1w = wstart[w + 1];
        int len = e1w - e0, chunk = (len + SPW - 1) / SPW;
        int a0 = e0 + sl * chunk;
        int a1 = a0 + chunk; if (a1 > e1w) a1 = e1w;
        for (int e = a0 + tid; e < a1; e += NT) {
            unsigned p = ebuf[e];
            float4 v = xd[p & SRC_MASK];
            int l3 = (int)(p >> 17) * 3;
            atomicAdd(&S[l3 + 0], v.x);
            atomicAdd(&S[l3 + 1], v.y);
            atomicAdd(&S[l3 + 2], v.z);
        }
        __syncthreads();
        float* dp = spart + (size_t)bi * (WNS * 3);
        for (int j = tid; j < WNS * 3; j += NT) dp[j] = S[j];
    }
    grid.sync();

    // ---- P7: S4 = self + 16 partials; fused 9-scalar BN stats ----
    {
        int n = bi * NT + tid;
        float st[9];
#pragma unroll
        for (int q = 0; q < 9; ++q) st[q] = 0.f;
        if (n < N_NODES) {
            int w = n >> 13, o = n & (WNS - 1);
            float4 self = xd[n];
            float sx = self.x, sy = self.y, sz = self.z;
            const float* sp = spart + (size_t)(w * SPW) * (WNS * 3) + (size_t)o * 3;
#pragma unroll
            for (int sl = 0; sl < SPW; ++sl) {
                const float* q2 = sp + (size_t)sl * (WNS * 3);
                sx += q2[0]; sy += q2[1]; sz += q2[2];
            }
            S4[n] = make_float4(sx, sy, sz, self.w);
            float ax = self.w * sx, ay = self.w * sy, az = self.w * sz;
            st[0] = ax; st[1] = ay; st[2] = az;
            st[3] = ax * ax; st[4] = ax * ay; st[5] = ax * az;
            st[6] = ay * ay; st[7] = ay * az; st[8] = az * az;
        }
        for (int m = 1; m < 64; m <<= 1)
#pragma unroll
            for (int q = 0; q < 9; ++q) st[q] += __shfl_xor(st[q], m);
        float (*ls)[9] = (float(*)[9])lds;
        int wv = tid >> 6;
        if ((tid & 63) == 0)
#pragma unroll
            for (int q = 0; q < 9; ++q) ls[wv][q] = st[q];
        __syncthreads();
        if (tid < 9) {
            float s = 0.f;
#pragma unroll
            for (int w2 = 0; w2 < 16; ++w2) s += ls[w2][tid];
            atomicAdd(&stats[tid], s);
        }
    }
    grid.sync();

    // ---- P8: BN-fold + PReLU streaming output ----
    {
        float* cb = (float*)lds;           // [128]
        if (tid < HID) {
            int c = tid;
            float m1x = stats[0], m1y = stats[1], m1z = stats[2];
            float Mxx = stats[3], Mxy = stats[4], Mxz = stats[5];
            float Myy = stats[6], Myz = stats[7], Mzz = stats[8];
            float w0 = W[c], w1 = W[HID + c], w2 = W[2 * HID + c];
            const float invn = 1.0f / (float)N_NODES;
            float m1w = m1x * w0 + m1y * w1 + m1z * w2;
            float mean = m1w * invn + bb[c];
            float quad = w0 * w0 * Mxx + w1 * w1 * Myy + w2 * w2 * Mzz
                       + 2.f * (w0 * w1 * Mxy + w0 * w2 * Mxz + w1 * w2 * Myz);
            float ex2 = quad * invn + 2.f * bb[c] * m1w * invn + bb[c] * bb[c];
            float var = ex2 - mean * mean;
            float sc = gamma[c] * rsqrtf(var + BN_EPS);
            cb[c] = w0 * sc;
            cb[HID + c] = w1 * sc;
            cb[2 * HID + c] = w2 * sc;
            cb[3 * HID + c] = bb[c] * sc + (beta[c] - mean * sc);
        }
        __syncthreads();
        float a = prelu[0];
        const int total = N_NODES * HID;
        for (int t = bi * NT + tid; t < total; t += NB * NT) {
            int n = t >> 5, c = t & 31;
            float4 s = S4[n];
            float y = s.w * (s.x * cb[c] + s.y * cb[HID + c] + s.z * cb[2 * HID + c])
                    + cb[3 * HID + c];
            out[t] = y >= 0.f ? y : a * y;
        }
    }
}

// ============================ fallback (round-4) path ============================

__global__ void fb_count_kernel(const int* __restrict__ dst, int* __restrict__ cnt) {
    int e = blockIdx.x * blockDim.x + threadIdx.x;
    if (e < N_EDGES) atomicAdd(&cnt[dst[e]], 1);
}

__global__ void fb_xd_kernel(const float* __restrict__ x, const int* __restrict__ cnt,
                             float4* __restrict__ xd, float4* __restrict__ S4) {
    int n = blockIdx.x * blockDim.x + threadIdx.x;
    if (n >= N_NODES) return;
    float rd = rsqrtf(1.0f + (float)cnt[n]);
    float4 v = make_float4(x[3 * n] * rd, x[3 * n + 1] * rd, x[3 * n + 2] * rd, rd);
    xd[n] = v;
    S4[n] = v;
}

__global__ void fb_scatter_kernel(const int* __restrict__ src, const int* __restrict__ dst,
                                  const float4* __restrict__ xd, float4* __restrict__ S4) {
    int e = blockIdx.x * blockDim.x + threadIdx.x;
    if (e >= N_EDGES) return;
    int s = src[e], d = dst[e];
    float4 v = xd[s];
    float* p = (float*)&S4[d];
    atomicAdd(p + 0, v.x);
    atomicAdd(p + 1, v.y);
    atomicAdd(p + 2, v.z);
}

__global__ void fb_stats_kernel(const float4* __restrict__ S4, float* __restrict__ stats) {
    __shared__ float ls[4][9];
    int tid = threadIdx.x;
    int n = blockIdx.x * blockDim.x + tid;
    float st[9];
#pragma unroll
    for (int q = 0; q < 9; ++q) st[q] = 0.f;
    if (n < N_NODES) {
        float4 s = S4[n];
        float ax = s.w * s.x, ay = s.w * s.y, az = s.w * s.z;
        st[0] = ax; st[1] = ay; st[2] = az;
        st[3] = ax * ax; st[4] = ax * ay; st[5] = ax * az;
        st[6] = ay * ay; st[7] = ay * az; st[8] = az * az;
    }
    for (int m = 1; m < 64; m <<= 1)
#pragma unroll
        for (int q = 0; q < 9; ++q) st[q] += __shfl_xor(st[q], m);
    int wv = tid >> 6;
    if ((tid & 63) == 0)
#pragma unroll
        for (int q = 0; q < 9; ++q) ls[wv][q] = st[q];
    __syncthreads();
    if (tid < 9) {
        float s = ls[0][tid] + ls[1][tid] + ls[2][tid] + ls[3][tid];
        atomicAdd(&stats[tid], s);
    }
}

__global__ void fb_out_kernel(const float4* __restrict__ S4, const float* __restrict__ stats,
                              const float* __restrict__ W, const float* __restrict__ bb,
                              const float* __restrict__ gamma, const float* __restrict__ beta,
                              const float* __restrict__ prelu, float* __restrict__ out) {
    __shared__ float cb[4 * HID];
    int tid = threadIdx.x;
    if (tid < HID) {
        int c = tid;
        float m1x = stats[0], m1y = stats[1], m1z = stats[2];
        float Mxx = stats[3], Mxy = stats[4], Mxz = stats[5];
        float Myy = stats[6], Myz = stats[7], Mzz = stats[8];
        float w0 = W[c], w1 = W[HID + c], w2 = W[2 * HID + c];
        const float invn = 1.0f / (float)N_NODES;
        float m1w = m1x * w0 + m1y * w1 + m1z * w2;
        float mean = m1w * invn + bb[c];
        float quad = w0 * w0 * Mxx + w1 * w1 * Myy + w2 * w2 * Mzz
                   + 2.f * (w0 * w1 * Mxy + w0 * w2 * Mxz + w1 * w2 * Myz);
        float ex2 = quad * invn + 2.f * bb[c] * m1w * invn + bb[c] * bb[c];
        float var = ex2 - mean * mean;
        float sc = gamma[c] * rsqrtf(var + BN_EPS);
        cb[c] = w0 * sc;
        cb[HID + c] = w1 * sc;
        cb[2 * HID + c] = w2 * sc;
        cb[3 * HID + c] = bb[c] * sc + (beta[c] - mean * sc);
    }
    __syncthreads();
    float a = prelu[0];
    int stride = gridDim.x * blockDim.x;
    for (int t = blockIdx.x * blockDim.x + tid; t < N_NODES * HID; t += stride) {
        int n = t >> 5, c = t & 31;
        float4 s = S4[n];
        float y = s.w * (s.x * cb[c] + s.y * cb[HID + c] + s.z * cb[2 * HID + c])
                + cb[3 * HID + c];
        out[t] = y >= 0.f ? y : a * y;
    }
}

// ============================ launch ============================

extern "C" void kernel_launch(void* const* d_in, const int* in_sizes, int n_in,
                              void* d_out, int out_size, void* d_ws, size_t ws_size,
                              hipStream_t stream) {
    const float* x     = (const float*)d_in[0];
    const int*   ei    = (const int*)d_in[1];   // [2, E]: src row then dst row
    const float* W     = (const float*)d_in[2];
    const float* b     = (const float*)d_in[3];
    const float* gamma = (const float*)d_in[4];
    const float* beta  = (const float*)d_in[5];
    const float* prelu = (const float*)d_in[6];

    const int* srcp = ei;
    const int* dstp = ei + N_EDGES;
    char* ws = (char*)d_ws;
    float* out = (float*)d_out;

    // ---- ws layout (fused path), total 36,884,800 B ----
    // stats  @ 0          float[16]        (64)
    // tot    @ 64         int[13]          -> pad 128
    // wstart @ 128        int[14]          -> pad 192
    // cnt    @ 192        int[NB*NW]       (10,816) -> 11,008
    // soff   @ 11,008     int[NB*NW]       (10,816) -> 21,824
    // ebuf   @ 21,824     u32[N_EDGES]     (6,400,000) -> 6,421,824
    // hpart  @ 6,421,824  int[NB*WNS]      (6,815,744) -> 13,237,568
    // spart  @ 13,237,568 float[NB*WNS*3]  (20,447,232) -> 33,684,800
    // xd     @ 33,684,800 float4[100000]   (1,600,000) -> 35,284,800  (16B-aligned)
    // S4     @ 35,284,800 float4[100000]   (1,600,000) -> 36,884,800  (16B-aligned)
    const size_t NEEDED = 36884800;

    if (ws_size >= NEEDED) {
        float*    stats  = (float*)(ws);
        int*      tot    = (int*)(ws + 64);
        int*      wstart = (int*)(ws + 128);
        int*      cnt    = (int*)(ws + 192);
        int*      soff   = (int*)(ws + 11008);
        unsigned* ebuf   = (unsigned*)(ws + 21824);
        int*      hpart  = (int*)(ws + 6421824);
        float*    spart  = (float*)(ws + 13237568);
        float4*   xd     = (float4*)(ws + 33684800);
        float4*   S4     = (float4*)(ws + 35284800);

        void* args[] = {(void*)&srcp, (void*)&dstp, (void*)&x, (void*)&W, (void*)&b,
                        (void*)&gamma, (void*)&beta, (void*)&prelu,
                        (void*)&stats, (void*)&cnt, (void*)&soff, (void*)&tot,
                        (void*)&wstart, (void*)&ebuf, (void*)&hpart, (void*)&spart,
                        (void*)&xd, (void*)&S4, (void*)&out};
        hipLaunchCooperativeKernel((void*)fused_kernel, dim3(NB), dim3(NT), args, 0, stream);
    } else {
        // fallback: round-4 direct-atomic path (ws need ~3.6 MB)
        int*    cnt   = (int*)(ws);
        float*  stats = (float*)(ws + 400000);
        float4* xd    = (float4*)(ws + 400640);
        float4* S4    = (float4*)(ws + 2000640);

        hipMemsetAsync(ws, 0, 400064, stream);
        fb_count_kernel<<<(N_EDGES + 255) / 256, 256, 0, stream>>>(dstp, cnt);
        fb_xd_kernel<<<(N_NODES + 255) / 256, 256, 0, stream>>>(x, cnt, xd, S4);
        fb_scatter_kernel<<<(N_EDGES + 255) / 256, 256, 0, stream>>>(srcp, dstp, xd, S4);
        fb_stats_kernel<<<(N_NODES + 255) / 256, 256, 0, stream>>>(S4, stats);
        fb_out_kernel<<<2048, 256, 0, stream>>>(S4, stats, W, b, gamma, beta, prelu, out);
    }
}